// Round 6
// baseline (168.472 us; speedup 1.0000x reference)
//
#include <hip/hip_runtime.h>
#include <math.h>

#define K_CODES 512
#define D_DIM   64
#define CHUNK   128   // codes staged per LDS chunk (32 KB)
#define TPP     4     // K-split: wave q scans 32-code slice of each chunk
#define PPB     128   // points per block = 64 lanes x 2 points/lane

// numpy pairwise-sum emulation for n=64 contiguous fp32 (AVX512 host build).
// FROZEN — bit-exact vs the np reference since R3. All adds __fadd_rn-guarded.
__device__ __forceinline__ float np_sum64_avx512(const float* sq) {
    float L[16];
#pragma unroll
    for (int j = 0; j < 16; ++j)
        L[j] = __fadd_rn(__fadd_rn(sq[j], sq[j + 16]),
                         __fadd_rn(sq[j + 32], sq[j + 48]));
    float m[8];
#pragma unroll
    for (int j = 0; j < 8; ++j) m[j] = __fadd_rn(L[j], L[j + 8]);
    float n4[4];
#pragma unroll
    for (int j = 0; j < 4; ++j) n4[j] = __fadd_rn(m[j], m[j + 4]);
    float o0 = __fadd_rn(n4[0], n4[2]);
    float o1 = __fadd_rn(n4[1], n4[3]);
    return __fadd_rn(o0, o1);
}

// ||e_k||^2 with the same numpy tree (squares rounded first). FROZEN (R3).
__global__ __launch_bounds__(256) void vq_norms_kernel(const float* __restrict__ cb,
                                                       float* __restrict__ norms) {
    int k = blockIdx.x * blockDim.x + threadIdx.x;
    if (k >= K_CODES) return;
    const float* row = cb + (size_t)k * D_DIM;
    float sq[D_DIM];
#pragma unroll
    for (int i = 0; i < D_DIM; ++i) sq[i] = __fmul_rn(row[i], row[i]);
    norms[k] = np_sum64_avx512(sq);
}

// R6: 2 points per lane (zA,zB pinned in VGPRs) x 4-way K-split.
// Rationale: R5 was LDS-pipe-bound — 1 broadcast ds_read_b128 per 4 wave-FMAs,
// 16 useful bytes per 4-12 cyc LDS slot, 12 waves/CU sharing one LDS pipe.
// Tp=2 halves reads/FMA to 1:8 and doubles indep FMA work per read batch.
// Per-k arithmetic chains FROZEN (R3 bit-exact): sequential ascending-i fmaf,
// dists = fl(fl(sz - fl(2dot)) + se), ascending-k first-min + (val,idx) merge.
__global__ __launch_bounds__(256, 3) void vq_argmin_kernel(
        const float* __restrict__ z, const float* __restrict__ cb,
        const float* __restrict__ norms, int* __restrict__ out, int n) {
    __shared__ float4 cb4[CHUNK * 16];    // 32 KB: [row][16 float4]
    __shared__ float4 nrm4[CHUNK / 4];    // 512 B
    __shared__ float  rv[2][256];         // 2 KB  (val reduce, A/B)
    __shared__ int    ri[2][256];         // 2 KB  (idx reduce, A/B)
    const float* nrm = (const float*)nrm4;

    const int tid  = threadIdx.x;
    const int lane = tid & 63;
    const int q    = tid >> 6;            // wave quarter 0..3 (wave-uniform)
    const int tA   = blockIdx.x * PPB + lane;
    const int tB   = tA + 64;
    const bool actA = (tA < n), actB = (tB < n);

    float zA[D_DIM], zB[D_DIM];
    if (actA) {
        const float4* zp = reinterpret_cast<const float4*>(z + (size_t)tA * D_DIM);
#pragma unroll
        for (int i = 0; i < 16; ++i) {
            float4 v = zp[i];
            zA[4 * i + 0] = v.x; zA[4 * i + 1] = v.y;
            zA[4 * i + 2] = v.z; zA[4 * i + 3] = v.w;
        }
    } else {
#pragma unroll
        for (int i = 0; i < D_DIM; ++i) zA[i] = 0.f;
    }
    if (actB) {
        const float4* zp = reinterpret_cast<const float4*>(z + (size_t)tB * D_DIM);
#pragma unroll
        for (int i = 0; i < 16; ++i) {
            float4 v = zp[i];
            zB[4 * i + 0] = v.x; zB[4 * i + 1] = v.y;
            zB[4 * i + 2] = v.z; zB[4 * i + 3] = v.w;
        }
    } else {
#pragma unroll
        for (int i = 0; i < D_DIM; ++i) zB[i] = 0.f;
    }

    // sz per point: squares rounded individually, then FROZEN tree.
    float sq[D_DIM];
#pragma unroll
    for (int i = 0; i < D_DIM; ++i) sq[i] = __fmul_rn(zA[i], zA[i]);
    const float szA = np_sum64_avx512(sq);
#pragma unroll
    for (int i = 0; i < D_DIM; ++i) sq[i] = __fmul_rn(zB[i], zB[i]);
    const float szB = np_sum64_avx512(sq);

    float bestA = INFINITY, bestB = INFINITY;
    int   biA   = 0,        biB   = 0;

    for (int c0 = 0; c0 < K_CODES; c0 += CHUNK) {
        __syncthreads();   // previous chunk fully consumed
        {
            const float4* src = reinterpret_cast<const float4*>(cb + (size_t)c0 * D_DIM);
#pragma unroll
            for (int j = 0; j < (CHUNK * 16) / 256; ++j)   // 8 float4 per thread
                cb4[tid + j * 256] = src[tid + j * 256];
            if (tid < CHUNK / 4)
                nrm4[tid] = reinterpret_cast<const float4*>(norms + c0)[tid];
        }
        __syncthreads();

        const int kbase = q * (CHUNK / TPP);               // 32-code slice
        for (int kk = kbase; kk < kbase + CHUNK / TPP; kk += 2) {
            const float4* e0 = cb4 + (kk + 0) * 16;
            const float4* e1 = cb4 + (kk + 1) * 16;
            float a0 = 0.f, a1 = 0.f, b0 = 0.f, b1 = 0.f;
#pragma unroll
            for (int g = 0; g < 16; ++g) {
                float4 v0 = e0[g], v1 = e1[g];
                float zA0 = zA[4 * g + 0], zA1 = zA[4 * g + 1];
                float zA2 = zA[4 * g + 2], zA3 = zA[4 * g + 3];
                float zB0 = zB[4 * g + 0], zB1 = zB[4 * g + 1];
                float zB2 = zB[4 * g + 2], zB3 = zB[4 * g + 3];
                a0 = fmaf(zA0, v0.x, a0); a0 = fmaf(zA1, v0.y, a0);
                a0 = fmaf(zA2, v0.z, a0); a0 = fmaf(zA3, v0.w, a0);
                a1 = fmaf(zA0, v1.x, a1); a1 = fmaf(zA1, v1.y, a1);
                a1 = fmaf(zA2, v1.z, a1); a1 = fmaf(zA3, v1.w, a1);
                b0 = fmaf(zB0, v0.x, b0); b0 = fmaf(zB1, v0.y, b0);
                b0 = fmaf(zB2, v0.z, b0); b0 = fmaf(zB3, v0.w, b0);
                b1 = fmaf(zB0, v1.x, b1); b1 = fmaf(zB1, v1.y, b1);
                b1 = fmaf(zB2, v1.z, b1); b1 = fmaf(zB3, v1.w, b1);
            }
            float nA = nrm[kk + 0], nB = nrm[kk + 1];
            float sA0 = __fadd_rn(__fsub_rn(szA, __fmul_rn(2.0f, a0)), nA);
            float sA1 = __fadd_rn(__fsub_rn(szA, __fmul_rn(2.0f, a1)), nB);
            float sB0 = __fadd_rn(__fsub_rn(szB, __fmul_rn(2.0f, b0)), nA);
            float sB1 = __fadd_rn(__fsub_rn(szB, __fmul_rn(2.0f, b1)), nB);
            if (sA0 < bestA) { bestA = sA0; biA = c0 + kk + 0; }
            if (sA1 < bestA) { bestA = sA1; biA = c0 + kk + 1; }
            if (sB0 < bestB) { bestB = sB0; biB = c0 + kk + 0; }
            if (sB1 < bestB) { bestB = sB1; biB = c0 + kk + 1; }
        }
    }

    // Exact cross-quarter merge: min value, ties -> lowest index (= first-min).
    rv[0][tid] = bestA; ri[0][tid] = biA;
    rv[1][tid] = bestB; ri[1][tid] = biB;
    __syncthreads();
    if (tid < 2 * 64) {
        const int which = tid >> 6;       // 0: point A set, 1: point B set
        const int pl    = tid & 63;
        float best = rv[which][pl];
        int   bi   = ri[which][pl];
#pragma unroll
        for (int j = 1; j < TPP; ++j) {
            float v  = rv[which][j * 64 + pl];
            int   id = ri[which][j * 64 + pl];
            if (v < best || (v == best && id < bi)) { best = v; bi = id; }
        }
        const int t = blockIdx.x * PPB + which * 64 + pl;
        if (t < n) out[t] = bi;
    }
}

extern "C" void kernel_launch(void* const* d_in, const int* in_sizes, int n_in,
                              void* d_out, int out_size, void* d_ws, size_t ws_size,
                              hipStream_t stream) {
    const float* z  = (const float*)d_in[0];
    const float* cb = (const float*)d_in[1];
    int n = in_sizes[0] / D_DIM;           // 131072 points
    float* norms = (float*)d_ws;           // 512 floats of scratch
    int* out = (int*)d_out;

    vq_norms_kernel<<<(K_CODES + 255) / 256, 256, 0, stream>>>(cb, norms);
    vq_argmin_kernel<<<(n + PPB - 1) / PPB, 256, 0, stream>>>(z, cb, norms, out, n);
}

// Round 7
// 163.407 us; speedup vs baseline: 1.0310x; 1.0310x over previous
//
#include <hip/hip_runtime.h>
#include <math.h>

#define K_CODES 512
#define D_DIM   64
#define CHUNK   128   // codes staged per LDS chunk (32 KB)
#define TPP     4     // K-split: wave q scans 32-code slice of each chunk
#define PPB     128   // points per block = 64 lanes x 2 points/lane

// FROZEN numerics (bit-exact vs np reference since R3):
//   sz  = numpy AVX512 pairwise tree over individually-rounded squares
//   dot = sequential ascending-i fmaf chain
//   dist= fl( fl(sz - fl(2*dot)) + se ), ascending-k first-min.

// sz from a register-resident z row WITHOUT a sq[64] temp array: computes
// the identical values L[j] = fl(fl(z_j^2)+fl(z_{j+16}^2)) + fl(fl(z_{j+32}^2)
// +fl(z_{j+48}^2)) then the same halving tree. 16 live temps, not 64.
__device__ __forceinline__ float np_sumsq64(const float* zarr) {
    float L[16];
#pragma unroll
    for (int j = 0; j < 16; ++j)
        L[j] = __fadd_rn(
            __fadd_rn(__fmul_rn(zarr[j],      zarr[j]),
                      __fmul_rn(zarr[j + 16], zarr[j + 16])),
            __fadd_rn(__fmul_rn(zarr[j + 32], zarr[j + 32]),
                      __fmul_rn(zarr[j + 48], zarr[j + 48])));
    float m[8];
#pragma unroll
    for (int j = 0; j < 8; ++j) m[j] = __fadd_rn(L[j], L[j + 8]);
    float n4[4];
#pragma unroll
    for (int j = 0; j < 4; ++j) n4[j] = __fadd_rn(m[j], m[j + 4]);
    return __fadd_rn(__fadd_rn(n4[0], n4[2]), __fadd_rn(n4[1], n4[3]));
}

__global__ __launch_bounds__(256) void vq_norms_kernel(const float* __restrict__ cb,
                                                       float* __restrict__ norms) {
    int k = blockIdx.x * blockDim.x + threadIdx.x;
    if (k >= K_CODES) return;
    norms[k] = np_sumsq64(cb + (size_t)k * D_DIM);
}

// R7 = R6 structure (2 pts/lane x 4-way K-split) with the spill fixed:
//  - no sq[64] (inline tree), szA computed before zB loads -> peak live ~150
//  - codebook staged via global_load_lds (no VGPR round-trip, linear dest)
//  - 4 FMA chains interleaved per element (chains stay ascending-i: FROZEN)
__global__ __launch_bounds__(256, 3) void vq_argmin_kernel(
        const float* __restrict__ z, const float* __restrict__ cb,
        const float* __restrict__ norms, int* __restrict__ out, int n) {
    __shared__ float4 cb4[CHUNK * 16];    // 32 KB: [row][16 float4]
    __shared__ float4 nrm4[CHUNK / 4];    // 512 B
    __shared__ float  rv[2][256];         // val reduce, A/B
    __shared__ int    ri[2][256];         // idx reduce, A/B
    const float* nrm = (const float*)nrm4;

    const int tid  = threadIdx.x;
    const int lane = tid & 63;
    const int q    = tid >> 6;            // wave quarter 0..3 (wave-uniform)
    const int tA   = blockIdx.x * PPB + lane;
    const int tB   = tA + 64;
    const bool actA = (tA < n), actB = (tB < n);

    float zA[D_DIM], zB[D_DIM];
    if (actA) {
        const float4* zp = reinterpret_cast<const float4*>(z + (size_t)tA * D_DIM);
#pragma unroll
        for (int i = 0; i < 16; ++i) {
            float4 v = zp[i];
            zA[4 * i + 0] = v.x; zA[4 * i + 1] = v.y;
            zA[4 * i + 2] = v.z; zA[4 * i + 3] = v.w;
        }
    } else {
#pragma unroll
        for (int i = 0; i < D_DIM; ++i) zA[i] = 0.f;
    }
    const float szA = np_sumsq64(zA);     // before zB loads: caps live regs

    if (actB) {
        const float4* zp = reinterpret_cast<const float4*>(z + (size_t)tB * D_DIM);
#pragma unroll
        for (int i = 0; i < 16; ++i) {
            float4 v = zp[i];
            zB[4 * i + 0] = v.x; zB[4 * i + 1] = v.y;
            zB[4 * i + 2] = v.z; zB[4 * i + 3] = v.w;
        }
    } else {
#pragma unroll
        for (int i = 0; i < D_DIM; ++i) zB[i] = 0.f;
    }
    const float szB = np_sumsq64(zB);

    float bestA = INFINITY, bestB = INFINITY;
    int   biA   = 0,        biB   = 0;

    for (int c0 = 0; c0 < K_CODES; c0 += CHUNK) {
        __syncthreads();   // previous chunk fully consumed
        {
            // Direct HBM->LDS DMA, 16B/lane, linear dest (wave-uniform base +
            // lane*16). No VGPR staging round-trip.
            const char* gsrc = (const char*)(cb + (size_t)c0 * D_DIM);
            char* lbase = (char*)cb4;
#pragma unroll
            for (int j = 0; j < 8; ++j) {
                size_t off = ((size_t)tid + (size_t)j * 256) * 16;
                __builtin_amdgcn_global_load_lds(
                    (const __attribute__((address_space(1))) void*)(gsrc + off),
                    (__attribute__((address_space(3))) void*)(lbase + off),
                    16, 0, 0);
            }
            if (tid < CHUNK / 4)
                nrm4[tid] = reinterpret_cast<const float4*>(norms + c0)[tid];
        }
        __syncthreads();   // barrier drains vmcnt -> LDS valid

        const int kbase = q * (CHUNK / TPP);               // 32-code slice
        for (int kk = kbase; kk < kbase + CHUNK / TPP; kk += 2) {
            const float4* e0 = cb4 + (kk + 0) * 16;
            const float4* e1 = cb4 + (kk + 1) * 16;
            float a0 = 0.f, a1 = 0.f, b0 = 0.f, b1 = 0.f;
#pragma unroll
            for (int g = 0; g < 16; ++g) {
                float4 v0 = e0[g], v1 = e1[g];
                // element-interleaved across 4 chains; each chain ascending-i
                a0 = fmaf(zA[4 * g + 0], v0.x, a0);
                a1 = fmaf(zA[4 * g + 0], v1.x, a1);
                b0 = fmaf(zB[4 * g + 0], v0.x, b0);
                b1 = fmaf(zB[4 * g + 0], v1.x, b1);
                a0 = fmaf(zA[4 * g + 1], v0.y, a0);
                a1 = fmaf(zA[4 * g + 1], v1.y, a1);
                b0 = fmaf(zB[4 * g + 1], v0.y, b0);
                b1 = fmaf(zB[4 * g + 1], v1.y, b1);
                a0 = fmaf(zA[4 * g + 2], v0.z, a0);
                a1 = fmaf(zA[4 * g + 2], v1.z, a1);
                b0 = fmaf(zB[4 * g + 2], v0.z, b0);
                b1 = fmaf(zB[4 * g + 2], v1.z, b1);
                a0 = fmaf(zA[4 * g + 3], v0.w, a0);
                a1 = fmaf(zA[4 * g + 3], v1.w, a1);
                b0 = fmaf(zB[4 * g + 3], v0.w, b0);
                b1 = fmaf(zB[4 * g + 3], v1.w, b1);
            }
            float nA = nrm[kk + 0], nB = nrm[kk + 1];
            float sA0 = __fadd_rn(__fsub_rn(szA, __fmul_rn(2.0f, a0)), nA);
            float sA1 = __fadd_rn(__fsub_rn(szA, __fmul_rn(2.0f, a1)), nB);
            float sB0 = __fadd_rn(__fsub_rn(szB, __fmul_rn(2.0f, b0)), nA);
            float sB1 = __fadd_rn(__fsub_rn(szB, __fmul_rn(2.0f, b1)), nB);
            if (sA0 < bestA) { bestA = sA0; biA = c0 + kk + 0; }
            if (sA1 < bestA) { bestA = sA1; biA = c0 + kk + 1; }
            if (sB0 < bestB) { bestB = sB0; biB = c0 + kk + 0; }
            if (sB1 < bestB) { bestB = sB1; biB = c0 + kk + 1; }
        }
    }

    // Exact cross-quarter merge: min value, ties -> lowest index (= first-min).
    rv[0][tid] = bestA; ri[0][tid] = biA;
    rv[1][tid] = bestB; ri[1][tid] = biB;
    __syncthreads();
    if (tid < 2 * 64) {
        const int which = tid >> 6;       // 0: point set A, 1: point set B
        const int pl    = tid & 63;
        float best = rv[which][pl];
        int   bi   = ri[which][pl];
#pragma unroll
        for (int j = 1; j < TPP; ++j) {
            float v  = rv[which][j * 64 + pl];
            int   id = ri[which][j * 64 + pl];
            if (v < best || (v == best && id < bi)) { best = v; bi = id; }
        }
        const int t = blockIdx.x * PPB + which * 64 + pl;
        if (t < n) out[t] = bi;
    }
}

extern "C" void kernel_launch(void* const* d_in, const int* in_sizes, int n_in,
                              void* d_out, int out_size, void* d_ws, size_t ws_size,
                              hipStream_t stream) {
    const float* z  = (const float*)d_in[0];
    const float* cb = (const float*)d_in[1];
    int n = in_sizes[0] / D_DIM;           // 131072 points
    float* norms = (float*)d_ws;           // 512 floats of scratch
    int* out = (int*)d_out;

    vq_norms_kernel<<<(K_CODES + 255) / 256, 256, 0, stream>>>(cb, norms);
    vq_argmin_kernel<<<(n + PPB - 1) / PPB, 256, 0, stream>>>(z, cb, norms, out, n);
}